// Round 1
// baseline (109.477 us; speedup 1.0000x reference)
//
#include <hip/hip_runtime.h>

constexpr int V  = 50257;   // vocab
constexpr int D  = 300;     // vocab dim
constexpr int KD = 512;     // decoder dim
constexpr int B  = 16;      // batch

constexpr int NB_ATT = (V * 4 + 255) / 256;   // 786 blocks in k_att
constexpr int NC  = 512;                      // wsum chunks
constexpr int RPC = (V + NC - 1) / NC;        // 99 rows per chunk

constexpr float NEG_HUGE = -1.0e30f;

// ws layout (float offsets)
constexpr size_t WS_QT   = 0;                              // 4800
constexpr size_t WS_STAT = 4800;                           // NB_ATT*16*2
constexpr size_t WS_MS   = WS_STAT + (size_t)NB_ATT * 32;  // 32
constexpr size_t WS_PART = WS_MS + 32;                     // NC*4800
constexpr size_t WS_TMP  = WS_PART + (size_t)NC * 4800;    // 16*4800

// ---------------------------------------------------------------------------
// K1: q_t[d*16+b] = sum_k dh[b,k]*Wdec[d,k] + bdec[d].  One wave per output.
__global__ void __launch_bounds__(256) k_query(
    const float* __restrict__ dh, const float* __restrict__ Wdec,
    const float* __restrict__ bdec, float* __restrict__ q_t)
{
    int wid  = (blockIdx.x * 256 + threadIdx.x) >> 6;
    int lane = threadIdx.x & 63;
    if (wid >= D * B) return;
    int d = wid >> 4, b = wid & 15;
    const float* wrow = Wdec + (size_t)d * KD;
    const float* hrow = dh + (size_t)b * KD;
    float s = 0.f;
    for (int k = lane; k < KD; k += 64) s += wrow[k] * hrow[k];
    #pragma unroll
    for (int off = 32; off; off >>= 1) s += __shfl_down(s, off, 64);
    if (lane == 0) q_t[d * 16 + b] = s + bdec[d];
}

// ---------------------------------------------------------------------------
// K2: att[b,v] = sum_d relu(E[v,d]+q[b,d])*wf[d] + bf, written to d_out alpha
// region (b-major). Also per-block softmax partials (m, s) per batch.
// Thread: v = gid>>2 (64 rows/block), bg = gid&3 -> batches bg*4..bg*4+3.
__global__ void __launch_bounds__(256) k_att(
    const float* __restrict__ E, const float* __restrict__ q_t,
    const float* __restrict__ wf, const float* __restrict__ bf,
    float* __restrict__ att, float* __restrict__ blkstats)
{
    __shared__ float sq[D * 16];      // q_t staged, d-major
    __shared__ float sw[D];
    __shared__ float satt[16][65];    // [b][v_local], padded
    int t = threadIdx.x;
    for (int i = t; i < D * 16; i += 256) sq[i] = q_t[i];
    for (int i = t; i < D; i += 256) sw[i] = wf[i];
    __syncthreads();

    int gid = blockIdx.x * 256 + t;
    int v = gid >> 2, bg = gid & 3;
    bool valid = v < V;
    float bfull = bf[0];
    float acc[4] = {0.f, 0.f, 0.f, 0.f};

    if (valid) {
        const float* erow = E + (size_t)v * D;
        for (int dd = 0; dd < D; dd += 4) {
            float4 e4 = *(const float4*)(erow + dd);
            float4 w4 = *(const float4*)(sw + dd);
            float e[4] = {e4.x, e4.y, e4.z, e4.w};
            float w[4] = {w4.x, w4.y, w4.z, w4.w};
            #pragma unroll
            for (int r = 0; r < 4; ++r) {
                float4 qr = *(const float4*)(sq + (dd + r) * 16 + bg * 4);
                acc[0] += fmaxf(e[r] + qr.x, 0.f) * w[r];
                acc[1] += fmaxf(e[r] + qr.y, 0.f) * w[r];
                acc[2] += fmaxf(e[r] + qr.z, 0.f) * w[r];
                acc[3] += fmaxf(e[r] + qr.w, 0.f) * w[r];
            }
        }
    }

    int vl = t >> 2;  // local row 0..63
    #pragma unroll
    for (int i = 0; i < 4; ++i) {
        float a = valid ? acc[i] + bfull : NEG_HUGE;
        if (valid) att[(size_t)(bg * 4 + i) * V + v] = a;
        satt[bg * 4 + i][vl] = a;
    }
    __syncthreads();

    // per-batch block reduce: 16 threads per batch
    int b = t >> 4, sub = t & 15;
    float x0 = satt[b][sub], x1 = satt[b][sub + 16];
    float x2 = satt[b][sub + 32], x3 = satt[b][sub + 48];
    float m = fmaxf(fmaxf(x0, x1), fmaxf(x2, x3));
    #pragma unroll
    for (int off = 8; off; off >>= 1) m = fmaxf(m, __shfl_xor(m, off, 16));
    float s = __expf(x0 - m) + __expf(x1 - m) + __expf(x2 - m) + __expf(x3 - m);
    #pragma unroll
    for (int off = 8; off; off >>= 1) s += __shfl_xor(s, off, 16);
    if (sub == 0) {
        blkstats[(size_t)(blockIdx.x * 16 + b) * 2]     = m;
        blkstats[(size_t)(blockIdx.x * 16 + b) * 2 + 1] = s;
    }
}

// ---------------------------------------------------------------------------
// K3: combine per-block stats -> M_b, 1/S_b
__global__ void __launch_bounds__(64) k_combine(
    const float* __restrict__ blkstats, float* __restrict__ MS)
{
    int b = blockIdx.x, lane = threadIdx.x;
    float m = NEG_HUGE;
    for (int c = lane; c < NB_ATT; c += 64)
        m = fmaxf(m, blkstats[(size_t)(c * 16 + b) * 2]);
    #pragma unroll
    for (int off = 32; off; off >>= 1) m = fmaxf(m, __shfl_xor(m, off, 64));
    float s = 0.f;
    for (int c = lane; c < NB_ATT; c += 64)
        s += blkstats[(size_t)(c * 16 + b) * 2 + 1] *
             __expf(blkstats[(size_t)(c * 16 + b) * 2] - m);
    #pragma unroll
    for (int off = 32; off; off >>= 1) s += __shfl_xor(s, off, 64);
    if (lane == 0) { MS[b * 2] = m; MS[b * 2 + 1] = 1.f / s; }
}

// ---------------------------------------------------------------------------
// K4: alpha = exp(att - M)*invS, in place in d_out alpha region.
__global__ void __launch_bounds__(256) k_alpha(
    float* __restrict__ att, const float* __restrict__ MS)
{
    int b = blockIdx.y;
    int v = blockIdx.x * 256 + threadIdx.x;
    if (v >= V) return;
    float M = MS[b * 2], invS = MS[b * 2 + 1];
    size_t i = (size_t)b * V + v;
    att[i] = __expf(att[i] - M) * invS;
}

// ---------------------------------------------------------------------------
// K5: partial weighted sums. Block c handles rows [c*RPC, ...), thread t<300
// owns column d=t with 16 batch accumulators. E coalesced, alpha uniform.
__global__ void __launch_bounds__(320) k_wsum(
    const float* __restrict__ E, const float* __restrict__ alpha,
    float* __restrict__ partials)
{
    int c = blockIdx.x, t = threadIdx.x;
    if (t >= D) return;
    int v0 = c * RPC, v1 = min(v0 + RPC, V);
    float acc[16];
    #pragma unroll
    for (int b = 0; b < 16; ++b) acc[b] = 0.f;
    for (int v = v0; v < v1; ++v) {
        float e = E[(size_t)v * D + t];
        #pragma unroll
        for (int b = 0; b < 16; ++b)
            acc[b] += alpha[(size_t)b * V + v] * e;
    }
    #pragma unroll
    for (int b = 0; b < 16; ++b)
        partials[(size_t)c * 4800 + b * 300 + t] = acc[b];
}

// ---------------------------------------------------------------------------
// K6/K7: two-stage reduction of partials over NC chunks.
__global__ void __launch_bounds__(256) k_red1(
    const float* __restrict__ partials, float* __restrict__ tmp)
{
    int o = blockIdx.x * 256 + threadIdx.x;
    if (o >= 4800) return;
    int y = blockIdx.y;
    float s = 0.f;
    for (int c = y * 32; c < y * 32 + 32; ++c)
        s += partials[(size_t)c * 4800 + o];
    tmp[(size_t)y * 4800 + o] = s;
}

__global__ void __launch_bounds__(256) k_red2(
    const float* __restrict__ tmp, float* __restrict__ out)
{
    int o = blockIdx.x * 256 + threadIdx.x;
    if (o >= 4800) return;
    float s = 0.f;
    #pragma unroll
    for (int y = 0; y < 16; ++y) s += tmp[(size_t)y * 4800 + o];
    out[o] = s;
}

// ---------------------------------------------------------------------------
extern "C" void kernel_launch(void* const* d_in, const int* in_sizes, int n_in,
                              void* d_out, int out_size, void* d_ws, size_t ws_size,
                              hipStream_t stream) {
    const float* dh   = (const float*)d_in[0];
    const float* E    = (const float*)d_in[1];
    const float* Wdec = (const float*)d_in[2];
    const float* bdec = (const float*)d_in[3];
    const float* wf   = (const float*)d_in[4];
    const float* bf   = (const float*)d_in[5];
    float* out = (float*)d_out;          // enc [0,4800), alpha [4800, ...)
    float* ws  = (float*)d_ws;

    float* q_t   = ws + WS_QT;
    float* stats = ws + WS_STAT;
    float* MS    = ws + WS_MS;
    float* part  = ws + WS_PART;
    float* tmp   = ws + WS_TMP;
    float* att   = out + 4800;

    k_query<<<(D * B + 3) / 4, 256, 0, stream>>>(dh, Wdec, bdec, q_t);
    k_att<<<NB_ATT, 256, 0, stream>>>(E, q_t, wf, bf, att, stats);
    k_combine<<<B, 64, 0, stream>>>(stats, MS);
    k_alpha<<<dim3((V + 255) / 256, B), 256, 0, stream>>>(att, MS);
    k_wsum<<<NC, 320, 0, stream>>>(E, att, part);
    k_red1<<<dim3(19, 16), 256, 0, stream>>>(part, tmp);
    k_red2<<<19, 256, 0, stream>>>(tmp, out);
}

// Round 2
// 85.442 us; speedup vs baseline: 1.2813x; 1.2813x over previous
//
#include <hip/hip_runtime.h>

constexpr int V  = 50257;   // vocab
constexpr int D  = 300;     // vocab dim
constexpr int KD = 512;     // decoder dim
constexpr int B  = 16;      // batch

constexpr int NB_ATT = (V + 63) / 64;         // 786 blocks in k_att (64 rows each)
constexpr int NC  = 512;                      // wsum chunks
constexpr int RPC = (V + NC - 1) / NC;        // 99 rows per chunk

constexpr float NEG_HUGE = -1.0e30f;

// ws layout (float offsets)
constexpr size_t WS_QT   = 0;                              // 4800
constexpr size_t WS_STAT = 4800;                           // NB_ATT*16*2
constexpr size_t WS_MS   = WS_STAT + (size_t)NB_ATT * 32;  // 32
constexpr size_t WS_PART = WS_MS + 32;                     // NC*4800
constexpr size_t WS_TMP  = WS_PART + (size_t)NC * 4800;    // 16*4800

struct f4 { float v[4]; };
__device__ __forceinline__ f4 ld4(const float* p) {
    float4 t = *(const float4*)p;
    return {t.x, t.y, t.z, t.w};
}

// ---------------------------------------------------------------------------
// K1: q_t[d*16+b] = sum_k dh[b,k]*Wdec[d,k] + bdec[d].  One wave per output.
__global__ void __launch_bounds__(256) k_query(
    const float* __restrict__ dh, const float* __restrict__ Wdec,
    const float* __restrict__ bdec, float* __restrict__ q_t)
{
    int wid  = (blockIdx.x * 256 + threadIdx.x) >> 6;
    int lane = threadIdx.x & 63;
    if (wid >= D * B) return;
    int d = wid >> 4, b = wid & 15;
    const float* wrow = Wdec + (size_t)d * KD;
    const float* hrow = dh + (size_t)b * KD;
    float s = 0.f;
    for (int k = lane; k < KD; k += 64) s += wrow[k] * hrow[k];
    #pragma unroll
    for (int off = 32; off; off >>= 1) s += __shfl_down(s, off, 64);
    if (lane == 0) q_t[d * 16 + b] = s + bdec[d];
}

// ---------------------------------------------------------------------------
// K2: att[b,v] = sum_d relu(E[v,d]+q[b,d])*wf[d] + bf.
// Block = 64 rows x 16 batches. Wave w = batch quad w.
// Lane = (rs, p): rs = row slot 0..15, p = d-phase 0..3.
// Thread: rows v0+rs+16j (j=0..3), batches 4*bg..4*bg+3, d in {16k+4p..+3}.
// E loads: 4 lanes of a row-slot cover contiguous 64B (coalesced); 4 rows
// per thread + 1-deep prefetch -> 8 loads in flight.
// q staged in LDS with column rotation so the 4 phase-broadcast b128 reads
// hit disjoint bank quads.
__global__ void __launch_bounds__(256) k_att(
    const float* __restrict__ E, const float* __restrict__ q_t,
    const float* __restrict__ wf, const float* __restrict__ bf,
    float* __restrict__ att, float* __restrict__ blkstats)
{
    __shared__ float sq[4800];      // [d][rotated batch-quad][4]
    __shared__ float sw[304];
    int t = threadIdx.x;
    for (int i = t; i < 4800; i += 256) {
        int d = i >> 4, b = i & 15;
        int bq = b >> 2, bl = b & 3;
        int col = (bq + (d >> 2)) & 3;
        sq[(d << 4) + (col << 2) + bl] = q_t[i];
    }
    for (int i = t; i < 304; i += 256) sw[i] = (i < 300) ? wf[i] : 0.f;
    __syncthreads();

    const int bg   = t >> 6;                 // wave id = batch quad
    const int lane = t & 63;
    const int rs   = lane >> 2;
    const int p    = lane & 3;
    const int p4   = p << 2;
    const int rot4 = ((bg + p) & 3) << 2;    // rotation col for this (bg,p)
    const int v0   = blockIdx.x << 6;

    const float* ep[4];
    bool rvalid[4];
    #pragma unroll
    for (int j = 0; j < 4; ++j) {
        int row = v0 + rs + (j << 4);
        rvalid[j] = row < V;
        ep[j] = E + (size_t)(rvalid[j] ? row : (V - 1)) * D;
    }

    float acc[4][4];
    #pragma unroll
    for (int j = 0; j < 4; ++j)
        #pragma unroll
        for (int b = 0; b < 4; ++b) acc[j][b] = 0.f;

    f4 ec[4], en[4];
    #pragma unroll
    for (int j = 0; j < 4; ++j) ec[j] = ld4(ep[j] + p4);

    for (int k = 0; k < 19; ++k) {
        int d0 = (k << 4) + p4;
        bool cur_ok = d0 < D;                // false only at k=18, p=3
        int dn = d0 + 16;
        int dns = (dn < D) ? dn : p4;        // safe dummy addr for prefetch
        #pragma unroll
        for (int j = 0; j < 4; ++j) en[j] = ld4(ep[j] + dns);
        if (cur_ok) {
            f4 wv = ld4(sw + d0);
            #pragma unroll
            for (int i = 0; i < 4; ++i) {
                f4 qv = ld4(sq + ((d0 + i) << 4) + rot4);
                float wi = wv.v[i];
                #pragma unroll
                for (int j = 0; j < 4; ++j) {
                    float e = ec[j].v[i];
                    #pragma unroll
                    for (int b = 0; b < 4; ++b)
                        acc[j][b] = fmaf(fmaxf(e + qv.v[b], 0.f), wi, acc[j][b]);
                }
            }
        }
        #pragma unroll
        for (int j = 0; j < 4; ++j) ec[j] = en[j];
    }

    // sum the 4 d-phases (lanes 4rs+0..3)
    #pragma unroll
    for (int j = 0; j < 4; ++j)
        #pragma unroll
        for (int b = 0; b < 4; ++b) {
            float s = acc[j][b];
            s += __shfl_xor(s, 1, 64);
            s += __shfl_xor(s, 2, 64);
            acc[j][b] = s;
        }

    // lane p owns batch 4*bg+p; write att + wave softmax partials
    float bfull = bf[0];
    float vj[4];
    float m_l = NEG_HUGE;
    #pragma unroll
    for (int j = 0; j < 4; ++j) {
        float s = (p == 0) ? acc[j][0] : (p == 1) ? acc[j][1]
                : (p == 2) ? acc[j][2] : acc[j][3];
        s += bfull;
        int row = v0 + rs + (j << 4);
        if (rvalid[j]) att[(size_t)((bg << 2) + p) * V + row] = s;
        vj[j] = rvalid[j] ? s : NEG_HUGE;
        m_l = fmaxf(m_l, vj[j]);
    }
    float s_l = 0.f;
    #pragma unroll
    for (int j = 0; j < 4; ++j) s_l += __expf(vj[j] - m_l);

    // reduce over 16 row-slots (lanes stride 4)
    #pragma unroll
    for (int sh = 2; sh < 6; ++sh) {
        int mask = 1 << sh;
        float mo = __shfl_xor(m_l, mask, 64);
        float so = __shfl_xor(s_l, mask, 64);
        float mn = fmaxf(m_l, mo);
        s_l = s_l * __expf(m_l - mn) + so * __expf(mo - mn);
        m_l = mn;
    }
    if (rs == 0) {
        size_t idx = ((size_t)blockIdx.x * 16 + (bg << 2) + p) * 2;
        blkstats[idx]     = m_l;
        blkstats[idx + 1] = s_l;
    }
}

// ---------------------------------------------------------------------------
// K3: combine per-block stats -> M_b, 1/S_b
__global__ void __launch_bounds__(64) k_combine(
    const float* __restrict__ blkstats, float* __restrict__ MS)
{
    int b = blockIdx.x, lane = threadIdx.x;
    float m = NEG_HUGE;
    for (int c = lane; c < NB_ATT; c += 64)
        m = fmaxf(m, blkstats[(size_t)(c * 16 + b) * 2]);
    #pragma unroll
    for (int off = 32; off; off >>= 1) m = fmaxf(m, __shfl_xor(m, off, 64));
    float s = 0.f;
    for (int c = lane; c < NB_ATT; c += 64)
        s += blkstats[(size_t)(c * 16 + b) * 2 + 1] *
             __expf(blkstats[(size_t)(c * 16 + b) * 2] - m);
    #pragma unroll
    for (int off = 32; off; off >>= 1) s += __shfl_xor(s, off, 64);
    if (lane == 0) { MS[b * 2] = m; MS[b * 2 + 1] = 1.f / s; }
}

// ---------------------------------------------------------------------------
// K4: alpha = exp(att - M)*invS, in place in d_out alpha region.
__global__ void __launch_bounds__(256) k_alpha(
    float* __restrict__ att, const float* __restrict__ MS)
{
    int b = blockIdx.y;
    int v = blockIdx.x * 256 + threadIdx.x;
    if (v >= V) return;
    float M = MS[b * 2], invS = MS[b * 2 + 1];
    size_t i = (size_t)b * V + v;
    att[i] = __expf(att[i] - M) * invS;
}

// ---------------------------------------------------------------------------
// K5: partial weighted sums. Block c handles rows [c*RPC, ...), thread t<300
// owns column d=t with 16 batch accumulators. E coalesced; 4x v-unroll gives
// 4 E loads in flight; alpha addresses are wave-uniform -> scalar loads.
__global__ void __launch_bounds__(320) k_wsum(
    const float* __restrict__ E, const float* __restrict__ alpha,
    float* __restrict__ partials)
{
    int c = blockIdx.x, t = threadIdx.x;
    if (t >= D) return;
    int v0 = c * RPC, v1 = min(v0 + RPC, V);
    float acc[16];
    #pragma unroll
    for (int b = 0; b < 16; ++b) acc[b] = 0.f;
    int v = v0;
    for (; v + 4 <= v1; v += 4) {
        float e0 = E[(size_t)v * D + t];
        float e1 = E[(size_t)(v + 1) * D + t];
        float e2 = E[(size_t)(v + 2) * D + t];
        float e3 = E[(size_t)(v + 3) * D + t];
        #pragma unroll
        for (int b = 0; b < 16; ++b) {
            const float* ap = alpha + (size_t)b * V + v;
            float a0 = ap[0], a1 = ap[1], a2 = ap[2], a3 = ap[3];
            acc[b] = fmaf(a0, e0, acc[b]);
            acc[b] = fmaf(a1, e1, acc[b]);
            acc[b] = fmaf(a2, e2, acc[b]);
            acc[b] = fmaf(a3, e3, acc[b]);
        }
    }
    for (; v < v1; ++v) {
        float e = E[(size_t)v * D + t];
        #pragma unroll
        for (int b = 0; b < 16; ++b)
            acc[b] = fmaf(alpha[(size_t)b * V + v], e, acc[b]);
    }
    #pragma unroll
    for (int b = 0; b < 16; ++b)
        partials[(size_t)c * 4800 + b * D + t] = acc[b];
}

// ---------------------------------------------------------------------------
// K6/K7: two-stage reduction of partials over NC chunks.
__global__ void __launch_bounds__(256) k_red1(
    const float* __restrict__ partials, float* __restrict__ tmp)
{
    int o = blockIdx.x * 256 + threadIdx.x;
    if (o >= 4800) return;
    int y = blockIdx.y;
    float s = 0.f;
    for (int c = y * 32; c < y * 32 + 32; ++c)
        s += partials[(size_t)c * 4800 + o];
    tmp[(size_t)y * 4800 + o] = s;
}

__global__ void __launch_bounds__(256) k_red2(
    const float* __restrict__ tmp, float* __restrict__ out)
{
    int o = blockIdx.x * 256 + threadIdx.x;
    if (o >= 4800) return;
    float s = 0.f;
    #pragma unroll
    for (int y = 0; y < 16; ++y) s += tmp[(size_t)y * 4800 + o];
    out[o] = s;
}

// ---------------------------------------------------------------------------
extern "C" void kernel_launch(void* const* d_in, const int* in_sizes, int n_in,
                              void* d_out, int out_size, void* d_ws, size_t ws_size,
                              hipStream_t stream) {
    const float* dh   = (const float*)d_in[0];
    const float* E    = (const float*)d_in[1];
    const float* Wdec = (const float*)d_in[2];
    const float* bdec = (const float*)d_in[3];
    const float* wf   = (const float*)d_in[4];
    const float* bf   = (const float*)d_in[5];
    float* out = (float*)d_out;          // enc [0,4800), alpha [4800, ...)
    float* ws  = (float*)d_ws;

    float* q_t   = ws + WS_QT;
    float* stats = ws + WS_STAT;
    float* MS    = ws + WS_MS;
    float* part  = ws + WS_PART;
    float* tmp   = ws + WS_TMP;
    float* att   = out + 4800;

    k_query<<<(D * B + 3) / 4, 256, 0, stream>>>(dh, Wdec, bdec, q_t);
    k_att<<<NB_ATT, 256, 0, stream>>>(E, q_t, wf, bf, att, stats);
    k_combine<<<B, 64, 0, stream>>>(stats, MS);
    k_alpha<<<dim3((V + 255) / 256, B), 256, 0, stream>>>(att, MS);
    k_wsum<<<NC, 320, 0, stream>>>(E, att, part);
    k_red1<<<dim3(19, 16), 256, 0, stream>>>(part, tmp);
    k_red2<<<19, 256, 0, stream>>>(tmp, out);
}

// Round 3
// 84.810 us; speedup vs baseline: 1.2908x; 1.0075x over previous
//
#include <hip/hip_runtime.h>

constexpr int V  = 50257;   // vocab
constexpr int D  = 300;     // vocab dim
constexpr int KD = 512;     // decoder dim
constexpr int B  = 16;      // batch

constexpr int ROWS = 32;                      // rows per k_att block
constexpr int NB_ATT = (V + ROWS - 1) / ROWS; // 1571 blocks
constexpr int NC  = 512;                      // wsum chunks
constexpr int RPC = (V + NC - 1) / NC;        // 99 rows per chunk

constexpr float NEG_HUGE = -1.0e30f;

// ws layout (float offsets)
constexpr size_t WS_QT   = 0;                              // 4800
constexpr size_t WS_STAT = 4800;                           // NB_ATT*16*2
constexpr size_t WS_MS   = WS_STAT + (size_t)NB_ATT * 32;  // 32
constexpr size_t WS_PART = WS_MS + 32;                     // NC*4800
constexpr size_t WS_TMP  = WS_PART + (size_t)NC * 4800;    // 16*4800

struct f4 { float v[4]; };
__device__ __forceinline__ f4 ld4(const float* p) {
    float4 t = *(const float4*)p;
    return {t.x, t.y, t.z, t.w};
}

// ---------------------------------------------------------------------------
// K1: q_t[d*16+b] = sum_k dh[b,k]*Wdec[d,k] + bdec[d].  One wave per output.
__global__ void __launch_bounds__(256) k_query(
    const float* __restrict__ dh, const float* __restrict__ Wdec,
    const float* __restrict__ bdec, float* __restrict__ q_t)
{
    int wid  = (blockIdx.x * 256 + threadIdx.x) >> 6;
    int lane = threadIdx.x & 63;
    if (wid >= D * B) return;
    int d = wid >> 4, b = wid & 15;
    const float* wrow = Wdec + (size_t)d * KD;
    const float* hrow = dh + (size_t)b * KD;
    float s = 0.f;
    for (int k = lane; k < KD; k += 64) s += wrow[k] * hrow[k];
    #pragma unroll
    for (int off = 32; off; off >>= 1) s += __shfl_down(s, off, 64);
    if (lane == 0) q_t[d * 16 + b] = s + bdec[d];
}

// ---------------------------------------------------------------------------
// K2: att[b,v] = sum_d relu(E[v,d]+q[b,d])*wf[d] + bf.
// Block = 32 rows x 16 batches, 256 threads. Wave w = batch quad.
// Lane = (rs, p): rs = row slot 0..15, p = d-phase 0..3.
// Thread: rows v0+rs, v0+rs+16; batches 4*bg..4*bg+3; d in {16k+4p..+3}.
// Latency hiding via occupancy: grid=1571 -> ~6 blocks/CU = 6 waves/SIMD.
__global__ void __launch_bounds__(256, 6) k_att(
    const float* __restrict__ E, const float* __restrict__ q_t,
    const float* __restrict__ wf, const float* __restrict__ bf,
    float* __restrict__ att, float* __restrict__ blkstats)
{
    __shared__ float sq[4800];      // [d][rotated batch-quad][4]
    __shared__ float sw[304];
    int t = threadIdx.x;
    for (int i4 = t * 4; i4 < 4800; i4 += 1024) {
        float4 qv = *(const float4*)(q_t + i4);
        int d = i4 >> 4, bq = (i4 & 15) >> 2;
        int col = (bq + (d >> 2)) & 3;
        *(float4*)(sq + (d << 4) + (col << 2)) = qv;
    }
    for (int i = t; i < 304; i += 256) sw[i] = (i < 300) ? wf[i] : 0.f;
    __syncthreads();

    const int bg   = t >> 6;                 // wave id = batch quad
    const int lane = t & 63;
    const int rs   = lane >> 2;
    const int p    = lane & 3;
    const int p4   = p << 2;
    const int rot4 = ((bg + p) & 3) << 2;    // rotation col for this (bg,p)
    const int v0   = blockIdx.x << 5;

    const float* ep[2];
    bool rvalid[2];
    #pragma unroll
    for (int j = 0; j < 2; ++j) {
        int row = v0 + rs + (j << 4);
        rvalid[j] = row < V;
        ep[j] = E + (size_t)(rvalid[j] ? row : (V - 1)) * D;
    }

    float acc[2][4];
    #pragma unroll
    for (int j = 0; j < 2; ++j)
        #pragma unroll
        for (int b = 0; b < 4; ++b) acc[j][b] = 0.f;

    f4 ec[2], en[2];
    #pragma unroll
    for (int j = 0; j < 2; ++j) ec[j] = ld4(ep[j] + p4);

    for (int k = 0; k < 19; ++k) {
        int d0 = (k << 4) + p4;
        bool cur_ok = d0 < D;                // false only at k=18, p=3
        int dn = d0 + 16;
        int dns = (dn < D) ? dn : p4;        // safe dummy addr for prefetch
        #pragma unroll
        for (int j = 0; j < 2; ++j) en[j] = ld4(ep[j] + dns);
        if (cur_ok) {
            f4 wv = ld4(sw + d0);
            #pragma unroll
            for (int i = 0; i < 4; ++i) {
                f4 qv = ld4(sq + ((d0 + i) << 4) + rot4);
                float wi = wv.v[i];
                #pragma unroll
                for (int j = 0; j < 2; ++j) {
                    float e = ec[j].v[i];
                    #pragma unroll
                    for (int b = 0; b < 4; ++b)
                        acc[j][b] = fmaf(fmaxf(e + qv.v[b], 0.f), wi, acc[j][b]);
                }
            }
        }
        #pragma unroll
        for (int j = 0; j < 2; ++j) ec[j] = en[j];
    }

    // sum the 4 d-phases (lanes 4rs+0..3)
    #pragma unroll
    for (int j = 0; j < 2; ++j)
        #pragma unroll
        for (int b = 0; b < 4; ++b) {
            float s = acc[j][b];
            s += __shfl_xor(s, 1, 64);
            s += __shfl_xor(s, 2, 64);
            acc[j][b] = s;
        }

    // lane p owns batch 4*bg+p; write att + wave softmax partials
    float bfull = bf[0];
    float vj[2];
    float m_l = NEG_HUGE;
    #pragma unroll
    for (int j = 0; j < 2; ++j) {
        float s = (p == 0) ? acc[j][0] : (p == 1) ? acc[j][1]
                : (p == 2) ? acc[j][2] : acc[j][3];
        s += bfull;
        int row = v0 + rs + (j << 4);
        if (rvalid[j]) att[(size_t)((bg << 2) + p) * V + row] = s;
        vj[j] = rvalid[j] ? s : NEG_HUGE;
        m_l = fmaxf(m_l, vj[j]);
    }
    float s_l = __expf(vj[0] - m_l) + __expf(vj[1] - m_l);

    // reduce over 16 row-slots (lanes stride 4)
    #pragma unroll
    for (int sh = 2; sh < 6; ++sh) {
        int mask = 1 << sh;
        float mo = __shfl_xor(m_l, mask, 64);
        float so = __shfl_xor(s_l, mask, 64);
        float mn = fmaxf(m_l, mo);
        s_l = s_l * __expf(m_l - mn) + so * __expf(mo - mn);
        m_l = mn;
    }
    if (rs == 0) {
        size_t idx = ((size_t)blockIdx.x * 16 + (bg << 2) + p) * 2;
        blkstats[idx]     = m_l;
        blkstats[idx + 1] = s_l;
    }
}

// ---------------------------------------------------------------------------
// K3: combine per-block stats -> M_b, 1/S_b
__global__ void __launch_bounds__(64) k_combine(
    const float* __restrict__ blkstats, float* __restrict__ MS)
{
    int b = blockIdx.x, lane = threadIdx.x;
    float m = NEG_HUGE;
    for (int c = lane; c < NB_ATT; c += 64)
        m = fmaxf(m, blkstats[(size_t)(c * 16 + b) * 2]);
    #pragma unroll
    for (int off = 32; off; off >>= 1) m = fmaxf(m, __shfl_xor(m, off, 64));
    float s = 0.f;
    for (int c = lane; c < NB_ATT; c += 64)
        s += blkstats[(size_t)(c * 16 + b) * 2 + 1] *
             __expf(blkstats[(size_t)(c * 16 + b) * 2] - m);
    #pragma unroll
    for (int off = 32; off; off >>= 1) s += __shfl_xor(s, off, 64);
    if (lane == 0) { MS[b * 2] = m; MS[b * 2 + 1] = 1.f / s; }
}

// ---------------------------------------------------------------------------
// K4: alpha = exp(att - M)*invS, in place in d_out alpha region.
__global__ void __launch_bounds__(256) k_alpha(
    float* __restrict__ att, const float* __restrict__ MS)
{
    int b = blockIdx.y;
    int v = blockIdx.x * 256 + threadIdx.x;
    if (v >= V) return;
    float M = MS[b * 2], invS = MS[b * 2 + 1];
    size_t i = (size_t)b * V + v;
    att[i] = __expf(att[i] - M) * invS;
}

// ---------------------------------------------------------------------------
// K5: partial weighted sums. Block c handles rows [c*RPC, ...), thread t<300
// owns column d=t with 16 batch accumulators. E coalesced; 8x v-unroll gives
// 8 E loads in flight; alpha addresses are wave-uniform -> scalar loads.
__global__ void __launch_bounds__(320) k_wsum(
    const float* __restrict__ E, const float* __restrict__ alpha,
    float* __restrict__ partials)
{
    int c = blockIdx.x, t = threadIdx.x;
    if (t >= D) return;
    int v0 = c * RPC, v1 = min(v0 + RPC, V);
    float acc[16];
    #pragma unroll
    for (int b = 0; b < 16; ++b) acc[b] = 0.f;
    int v = v0;
    for (; v + 8 <= v1; v += 8) {
        float e[8];
        #pragma unroll
        for (int r = 0; r < 8; ++r) e[r] = E[(size_t)(v + r) * D + t];
        #pragma unroll
        for (int b = 0; b < 16; ++b) {
            const float* ap = alpha + (size_t)b * V + v;
            float a = acc[b];
            #pragma unroll
            for (int r = 0; r < 8; ++r) a = fmaf(ap[r], e[r], a);
            acc[b] = a;
        }
    }
    for (; v < v1; ++v) {
        float e = E[(size_t)v * D + t];
        #pragma unroll
        for (int b = 0; b < 16; ++b)
            acc[b] = fmaf(alpha[(size_t)b * V + v], e, acc[b]);
    }
    #pragma unroll
    for (int b = 0; b < 16; ++b)
        partials[(size_t)c * 4800 + b * D + t] = acc[b];
}

// ---------------------------------------------------------------------------
// K6/K7: two-stage reduction of partials over NC chunks, float4-wide.
__global__ void __launch_bounds__(256) k_red1(
    const float* __restrict__ partials, float* __restrict__ tmp)
{
    int o4 = blockIdx.x * 256 + threadIdx.x;   // quad index, 1200 total
    if (o4 >= 1200) return;
    int y = blockIdx.y;
    float4 s = {0.f, 0.f, 0.f, 0.f};
    for (int c = y * 32; c < y * 32 + 32; ++c) {
        float4 p = *(const float4*)(partials + (size_t)c * 4800 + o4 * 4);
        s.x += p.x; s.y += p.y; s.z += p.z; s.w += p.w;
    }
    *(float4*)(tmp + (size_t)y * 4800 + o4 * 4) = s;
}

__global__ void __launch_bounds__(256) k_red2(
    const float* __restrict__ tmp, float* __restrict__ out)
{
    int o4 = blockIdx.x * 256 + threadIdx.x;
    if (o4 >= 1200) return;
    float4 s = {0.f, 0.f, 0.f, 0.f};
    #pragma unroll
    for (int y = 0; y < 16; ++y) {
        float4 p = *(const float4*)(tmp + (size_t)y * 4800 + o4 * 4);
        s.x += p.x; s.y += p.y; s.z += p.z; s.w += p.w;
    }
    *(float4*)(out + o4 * 4) = s;
}

// ---------------------------------------------------------------------------
extern "C" void kernel_launch(void* const* d_in, const int* in_sizes, int n_in,
                              void* d_out, int out_size, void* d_ws, size_t ws_size,
                              hipStream_t stream) {
    const float* dh   = (const float*)d_in[0];
    const float* E    = (const float*)d_in[1];
    const float* Wdec = (const float*)d_in[2];
    const float* bdec = (const float*)d_in[3];
    const float* wf   = (const float*)d_in[4];
    const float* bf   = (const float*)d_in[5];
    float* out = (float*)d_out;          // enc [0,4800), alpha [4800, ...)
    float* ws  = (float*)d_ws;

    float* q_t   = ws + WS_QT;
    float* stats = ws + WS_STAT;
    float* MS    = ws + WS_MS;
    float* part  = ws + WS_PART;
    float* tmp   = ws + WS_TMP;
    float* att   = out + 4800;

    k_query<<<(D * B + 3) / 4, 256, 0, stream>>>(dh, Wdec, bdec, q_t);
    k_att<<<NB_ATT, 256, 0, stream>>>(E, q_t, wf, bf, att, stats);
    k_combine<<<B, 64, 0, stream>>>(stats, MS);
    k_alpha<<<dim3((V + 255) / 256, B), 256, 0, stream>>>(att, MS);
    k_wsum<<<NC, 320, 0, stream>>>(E, att, part);
    k_red1<<<dim3(5, 16), 256, 0, stream>>>(part, tmp);
    k_red2<<<5, 256, 0, stream>>>(tmp, out);
}

// Round 4
// 73.431 us; speedup vs baseline: 1.4909x; 1.1550x over previous
//
#include <hip/hip_runtime.h>

constexpr int V  = 50257;   // vocab
constexpr int D  = 300;     // vocab dim
constexpr int KD = 512;     // decoder dim
constexpr int B  = 16;      // batch

constexpr int ROWS = 32;                      // rows per k_att block
constexpr int NB_ATT = (V + ROWS - 1) / ROWS; // 1571 blocks
constexpr int NC  = 512;                      // wsum chunks
constexpr int RPC = (V + NC - 1) / NC;        // 99 rows per chunk

constexpr float NEG_HUGE = -1.0e30f;

// ws layout (float offsets)
constexpr size_t WS_QT   = 0;                              // 4800
constexpr size_t WS_STAT = 4800;                           // NB_ATT*16*2
constexpr size_t WS_MS   = WS_STAT + (size_t)NB_ATT * 32;  // 32
constexpr size_t WS_PART = WS_MS + 32;                     // NC*4800
constexpr size_t WS_TMP  = WS_PART + (size_t)NC * 4800;    // 16*4800

struct f4 { float v[4]; };
__device__ __forceinline__ f4 ld4(const float* p) {
    float4 t = *(const float4*)p;
    return {t.x, t.y, t.z, t.w};
}

// ---------------------------------------------------------------------------
// K1: q_t[d*16+b] = sum_k dh[b,k]*Wdec[d,k] + bdec[d].  One wave per output.
__global__ void __launch_bounds__(256) k_query(
    const float* __restrict__ dh, const float* __restrict__ Wdec,
    const float* __restrict__ bdec, float* __restrict__ q_t)
{
    int wid  = (blockIdx.x * 256 + threadIdx.x) >> 6;
    int lane = threadIdx.x & 63;
    if (wid >= D * B) return;
    int d = wid >> 4, b = wid & 15;
    const float* wrow = Wdec + (size_t)d * KD;
    const float* hrow = dh + (size_t)b * KD;
    float s = 0.f;
    for (int k = lane; k < KD; k += 64) s += wrow[k] * hrow[k];
    #pragma unroll
    for (int off = 32; off; off >>= 1) s += __shfl_down(s, off, 64);
    if (lane == 0) q_t[d * 16 + b] = s + bdec[d];
}

// ---------------------------------------------------------------------------
// K2: att[b,v] = sum_d relu(E[v,d]+q[b,d])*wf[d] + bf.
// Block = 32 rows x 16 batches, 256 threads. Wave = batch quad.
// Lane = (rs, p): rs = row slot 0..15, p = d-phase 0..3.
// BRANCHLESS k-loop: q/w zero-padded to d=304 in LDS; prefetch address
// clamped to d=0 (its weight is 0, contribution is exactly 0).
__global__ void __launch_bounds__(256) k_att(
    const float* __restrict__ E, const float* __restrict__ q_t,
    const float* __restrict__ wf, const float* __restrict__ bf,
    float* __restrict__ att, float* __restrict__ blkstats)
{
    __shared__ float sq[4864];      // 304 d x 16 b, rotated, zero-padded
    __shared__ float sw[304];
    int t = threadIdx.x;
    for (int i4 = t * 4; i4 < 4800; i4 += 1024) {
        float4 qv = *(const float4*)(q_t + i4);
        int d = i4 >> 4, bq = (i4 & 15) >> 2;
        int col = (bq + (d >> 2)) & 3;
        *(float4*)(sq + (d << 4) + (col << 2)) = qv;
    }
    if (t < 64) sq[4800 + t] = 0.f;
    for (int i = t; i < 304; i += 256) sw[i] = (i < 300) ? wf[i] : 0.f;
    __syncthreads();

    const int bg   = t >> 6;                 // wave id = batch quad
    const int lane = t & 63;
    const int rs   = lane >> 2;
    const int p    = lane & 3;
    const int p4   = p << 2;
    const int rot4 = ((bg + p) & 3) << 2;    // rotation col for this (bg,p)
    const int v0   = blockIdx.x << 5;

    const float* ep[2];
    bool rvalid[2];
    #pragma unroll
    for (int j = 0; j < 2; ++j) {
        int row = v0 + rs + (j << 4);
        rvalid[j] = row < V;
        ep[j] = E + (size_t)(rvalid[j] ? row : (V - 1)) * D;
    }

    float acc[2][4];
    #pragma unroll
    for (int j = 0; j < 2; ++j)
        #pragma unroll
        for (int b = 0; b < 4; ++b) acc[j][b] = 0.f;

    f4 ec[2], en[2];
    #pragma unroll
    for (int j = 0; j < 2; ++j) ec[j] = ld4(ep[j] + p4);

    #pragma unroll 2
    for (int k = 0; k < 19; ++k) {
        int d0 = (k << 4) + p4;
        int dn = d0 + 16;
        int dns = (dn < D) ? dn : 0;         // in-bounds clamp; pad weight = 0
        #pragma unroll
        for (int j = 0; j < 2; ++j) en[j] = ld4(ep[j] + dns);

        f4 wv = ld4(sw + d0);
        #pragma unroll
        for (int i = 0; i < 4; ++i) {
            f4 qv = ld4(sq + ((d0 + i) << 4) + rot4);
            float wi = wv.v[i];
            #pragma unroll
            for (int j = 0; j < 2; ++j) {
                float e = ec[j].v[i];
                #pragma unroll
                for (int b = 0; b < 4; ++b)
                    acc[j][b] = fmaf(fmaxf(e + qv.v[b], 0.f), wi, acc[j][b]);
            }
        }
        #pragma unroll
        for (int j = 0; j < 2; ++j) ec[j] = en[j];
    }

    // sum the 4 d-phases (lanes 4rs+0..3)
    #pragma unroll
    for (int j = 0; j < 2; ++j)
        #pragma unroll
        for (int b = 0; b < 4; ++b) {
            float s = acc[j][b];
            s += __shfl_xor(s, 1, 64);
            s += __shfl_xor(s, 2, 64);
            acc[j][b] = s;
        }

    // lane p owns batch 4*bg+p; write att + wave softmax partials
    float bfull = bf[0];
    float vj[2];
    float m_l = NEG_HUGE;
    #pragma unroll
    for (int j = 0; j < 2; ++j) {
        float s = (p == 0) ? acc[j][0] : (p == 1) ? acc[j][1]
                : (p == 2) ? acc[j][2] : acc[j][3];
        s += bfull;
        int row = v0 + rs + (j << 4);
        if (rvalid[j]) att[(size_t)((bg << 2) + p) * V + row] = s;
        vj[j] = rvalid[j] ? s : NEG_HUGE;
        m_l = fmaxf(m_l, vj[j]);
    }
    float s_l = __expf(vj[0] - m_l) + __expf(vj[1] - m_l);

    // reduce over 16 row-slots (lanes stride 4)
    #pragma unroll
    for (int sh = 2; sh < 6; ++sh) {
        int mask = 1 << sh;
        float mo = __shfl_xor(m_l, mask, 64);
        float so = __shfl_xor(s_l, mask, 64);
        float mn = fmaxf(m_l, mo);
        s_l = s_l * __expf(m_l - mn) + so * __expf(mo - mn);
        m_l = mn;
    }
    if (rs == 0) {
        size_t idx = ((size_t)blockIdx.x * 16 + (bg << 2) + p) * 2;
        blkstats[idx]     = m_l;
        blkstats[idx + 1] = s_l;
    }
}

// ---------------------------------------------------------------------------
// K3: combine per-block stats -> M_b, 1/S_b
__global__ void __launch_bounds__(64) k_combine(
    const float* __restrict__ blkstats, float* __restrict__ MS)
{
    int b = blockIdx.x, lane = threadIdx.x;
    float m = NEG_HUGE;
    for (int c = lane; c < NB_ATT; c += 64)
        m = fmaxf(m, blkstats[(size_t)(c * 16 + b) * 2]);
    #pragma unroll
    for (int off = 32; off; off >>= 1) m = fmaxf(m, __shfl_xor(m, off, 64));
    float s = 0.f;
    for (int c = lane; c < NB_ATT; c += 64)
        s += blkstats[(size_t)(c * 16 + b) * 2 + 1] *
             __expf(blkstats[(size_t)(c * 16 + b) * 2] - m);
    #pragma unroll
    for (int off = 32; off; off >>= 1) s += __shfl_xor(s, off, 64);
    if (lane == 0) { MS[b * 2] = m; MS[b * 2 + 1] = 1.f / s; }
}

// ---------------------------------------------------------------------------
// K4 (fused alpha + wsum): per chunk c of RPC rows:
//   phase 1: alpha = exp(att-M)*invS, written in place AND staged in LDS
//   phase 2: thread t<300 owns column d=t, accumulates 16 batch partials.
__global__ void __launch_bounds__(320) k_awsum(
    const float* __restrict__ E, float* __restrict__ att,
    const float* __restrict__ MS, float* __restrict__ partials)
{
    __shared__ float sal[RPC * 16];   // [vv][b]
    int c = blockIdx.x, t = threadIdx.x;
    int v0 = c * RPC;
    int n = V - v0;
    if (n > RPC) n = RPC;
    if (n < 0) n = 0;

    for (int i = t; i < RPC * 16; i += 320) {
        int b = i / RPC, vv = i - b * RPC;
        float a = 0.f;
        if (vv < n) {
            float M = MS[b * 2], invS = MS[b * 2 + 1];
            size_t gi = (size_t)b * V + v0 + vv;
            a = __expf(att[gi] - M) * invS;
            att[gi] = a;
        }
        sal[vv * 16 + b] = a;
    }
    __syncthreads();

    if (t < D) {
        float acc[16];
        #pragma unroll
        for (int b = 0; b < 16; ++b) acc[b] = 0.f;
        #pragma unroll 4
        for (int vv = 0; vv < n; ++vv) {
            float e = E[(size_t)(v0 + vv) * D + t];
            const float* ap = sal + vv * 16;
            f4 a0 = ld4(ap), a1 = ld4(ap + 4), a2 = ld4(ap + 8), a3 = ld4(ap + 12);
            #pragma unroll
            for (int b = 0; b < 4; ++b) {
                acc[b]      = fmaf(a0.v[b], e, acc[b]);
                acc[b + 4]  = fmaf(a1.v[b], e, acc[b + 4]);
                acc[b + 8]  = fmaf(a2.v[b], e, acc[b + 8]);
                acc[b + 12] = fmaf(a3.v[b], e, acc[b + 12]);
            }
        }
        #pragma unroll
        for (int b = 0; b < 16; ++b)
            partials[(size_t)c * 4800 + b * D + t] = acc[b];
    }
}

// ---------------------------------------------------------------------------
// K5/K6: two-stage reduction of partials over NC chunks, float4-wide.
__global__ void __launch_bounds__(256) k_red1(
    const float* __restrict__ partials, float* __restrict__ tmp)
{
    int o4 = blockIdx.x * 256 + threadIdx.x;   // quad index, 1200 total
    if (o4 >= 1200) return;
    int y = blockIdx.y;
    float4 s = {0.f, 0.f, 0.f, 0.f};
    for (int c = y * 32; c < y * 32 + 32; ++c) {
        float4 p = *(const float4*)(partials + (size_t)c * 4800 + o4 * 4);
        s.x += p.x; s.y += p.y; s.z += p.z; s.w += p.w;
    }
    *(float4*)(tmp + (size_t)y * 4800 + o4 * 4) = s;
}

__global__ void __launch_bounds__(256) k_red2(
    const float* __restrict__ tmp, float* __restrict__ out)
{
    int o4 = blockIdx.x * 256 + threadIdx.x;
    if (o4 >= 1200) return;
    float4 s = {0.f, 0.f, 0.f, 0.f};
    #pragma unroll
    for (int y = 0; y < 16; ++y) {
        float4 p = *(const float4*)(tmp + (size_t)y * 4800 + o4 * 4);
        s.x += p.x; s.y += p.y; s.z += p.z; s.w += p.w;
    }
    *(float4*)(out + o4 * 4) = s;
}

// ---------------------------------------------------------------------------
extern "C" void kernel_launch(void* const* d_in, const int* in_sizes, int n_in,
                              void* d_out, int out_size, void* d_ws, size_t ws_size,
                              hipStream_t stream) {
    const float* dh   = (const float*)d_in[0];
    const float* E    = (const float*)d_in[1];
    const float* Wdec = (const float*)d_in[2];
    const float* bdec = (const float*)d_in[3];
    const float* wf   = (const float*)d_in[4];
    const float* bf   = (const float*)d_in[5];
    float* out = (float*)d_out;          // enc [0,4800), alpha [4800, ...)
    float* ws  = (float*)d_ws;

    float* q_t   = ws + WS_QT;
    float* stats = ws + WS_STAT;
    float* MS    = ws + WS_MS;
    float* part  = ws + WS_PART;
    float* tmp   = ws + WS_TMP;
    float* att   = out + 4800;

    k_query<<<(D * B + 3) / 4, 256, 0, stream>>>(dh, Wdec, bdec, q_t);
    k_att<<<NB_ATT, 256, 0, stream>>>(E, q_t, wf, bf, att, stats);
    k_combine<<<B, 64, 0, stream>>>(stats, MS);
    k_awsum<<<NC, 320, 0, stream>>>(E, att, MS, part);
    k_red1<<<dim3(5, 16), 256, 0, stream>>>(part, tmp);
    k_red2<<<5, 256, 0, stream>>>(tmp, out);
}